// Round 1
// baseline (726.262 us; speedup 1.0000x reference)
//
#include <hip/hip_runtime.h>
#include <math.h>

#define N_NODES 4096
#define IN_DIM  512
#define H_DIM   256
#define OUT_DIM 64
#define SCAD_Af 3.7f
#define EPSf    1e-8f
#define NBINS   65536
#define MAXE    524288

// ---------------------------------------------------------------------------
// Degree per row (A is 0/1 with zero diagonal). D = deg + 1 (add_loops).
__global__ void k_deg(const float* __restrict__ A, int* __restrict__ rowcnt,
                      float* __restrict__ D, float* __restrict__ isD) {
    int i = blockIdx.x;
    const float* row = A + (size_t)i * N_NODES;
    int cnt = 0;
    for (int j = threadIdx.x; j < N_NODES; j += blockDim.x)
        cnt += (row[j] != 0.0f) ? 1 : 0;
    // wave reduce (64 lanes)
    for (int off = 32; off; off >>= 1) cnt += __shfl_down(cnt, off, 64);
    __shared__ int sh[4];
    int wid = threadIdx.x >> 6, lane = threadIdx.x & 63;
    if (lane == 0) sh[wid] = cnt;
    __syncthreads();
    if (threadIdx.x == 0) {
        int t = 0;
        for (int w = 0; w < 4; w++) t += sh[w];
        rowcnt[i] = t;
        float d = (float)t + 1.0f;
        D[i] = d;
        isD[i] = 1.0f / sqrtf(d);
    }
}

// Exclusive scan of 4096 ints -> rowptr[0..4096]. Single block, 1024 threads.
__global__ void k_scan(const int* __restrict__ rowcnt, int* __restrict__ rowptr) {
    __shared__ int sh[1024];
    int t = threadIdx.x;
    int v0 = rowcnt[4 * t + 0], v1 = rowcnt[4 * t + 1];
    int v2 = rowcnt[4 * t + 2], v3 = rowcnt[4 * t + 3];
    int s = v0 + v1 + v2 + v3;
    sh[t] = s;
    __syncthreads();
    for (int off = 1; off < 1024; off <<= 1) {
        int x = 0;
        if (t >= off) x = sh[t - off];
        __syncthreads();
        sh[t] += x;
        __syncthreads();
    }
    int excl = sh[t] - s;
    rowptr[4 * t + 0] = excl;
    rowptr[4 * t + 1] = excl + v0;
    rowptr[4 * t + 2] = excl + v0 + v1;
    rowptr[4 * t + 3] = excl + v0 + v1 + v2;
    if (t == 1023) rowptr[N_NODES] = sh[1023];
}

// Fill CSR (row index + col index per edge; order within row is irrelevant).
__global__ void k_fill(const float* __restrict__ A, const int* __restrict__ rowptr,
                       int* __restrict__ rowIdx, int* __restrict__ colIdx) {
    int i = blockIdx.x;
    __shared__ int base, cnt;
    if (threadIdx.x == 0) { base = rowptr[i]; cnt = 0; }
    __syncthreads();
    const float* row = A + (size_t)i * N_NODES;
    for (int j = threadIdx.x; j < N_NODES; j += blockDim.x) {
        if (row[j] != 0.0f) {
            int p = atomicAdd(&cnt, 1);
            rowIdx[base + p] = i;
            colIdx[base + p] = j;
        }
    }
}

// ---------------------------------------------------------------------------
// fp32 tiled GEMM: C[M,Nn] = act(Am[M,K] @ Bm[K,Nn] + bias). BM=BN=64, BK=16,
// 256 threads, 4x4 micro-tile.
template <int Nn, int K, bool RELU>
__global__ void k_gemm(const float* __restrict__ Am, const float* __restrict__ Bm,
                       const float* __restrict__ bias, float* __restrict__ Cm) {
    __shared__ float As[16][68];
    __shared__ float Bs[16][64];
    int tx = threadIdx.x & 15, ty = threadIdx.x >> 4;
    int bm = blockIdx.y * 64, bn = blockIdx.x * 64;
    float acc[4][4] = {};
    for (int k0 = 0; k0 < K; k0 += 16) {
        {   // A tile 64x16, float4 per thread, store transposed
            int r = threadIdx.x >> 2, kv = threadIdx.x & 3;
            float4 v = *(const float4*)(Am + (size_t)(bm + r) * K + k0 + kv * 4);
            As[kv * 4 + 0][r] = v.x;
            As[kv * 4 + 1][r] = v.y;
            As[kv * 4 + 2][r] = v.z;
            As[kv * 4 + 3][r] = v.w;
        }
        {   // B tile 16x64, natural layout
            int kk = threadIdx.x >> 4, nv = threadIdx.x & 15;
            *(float4*)&Bs[kk][nv * 4] =
                *(const float4*)(Bm + (size_t)(k0 + kk) * Nn + bn + nv * 4);
        }
        __syncthreads();
#pragma unroll
        for (int kk = 0; kk < 16; kk++) {
            float a[4], b[4];
#pragma unroll
            for (int u = 0; u < 4; u++) { a[u] = As[kk][ty * 4 + u]; b[u] = Bs[kk][tx * 4 + u]; }
#pragma unroll
            for (int u = 0; u < 4; u++)
#pragma unroll
                for (int v = 0; v < 4; v++) acc[u][v] += a[u] * b[v];
        }
        __syncthreads();
    }
#pragma unroll
    for (int u = 0; u < 4; u++) {
        int m = bm + ty * 4 + u;
#pragma unroll
        for (int v = 0; v < 4; v++) {
            int n = bn + tx * 4 + v;
            float x = acc[u][v] + bias[n];
            if (RELU) x = fmaxf(x, 0.0f);
            Cm[(size_t)m * Nn + n] = x;
        }
    }
}

// ---------------------------------------------------------------------------
// Row-normalize: Fu_i = (Fc_i / sqrt(D_i)) / max(||Fc_i / sqrt(D_i)||, EPS)
__global__ void k_norm(const float* __restrict__ Fc, const float* __restrict__ isD,
                       float* __restrict__ Fu) {
    int gid = blockIdx.x * blockDim.x + threadIdx.x;
    int i = gid >> 6, c = gid & 63;
    float fn = Fc[(size_t)i * 64 + c] * isD[i];
    float s = fn * fn;
    for (int off = 32; off; off >>= 1) s += __shfl_xor(s, off, 64);
    float nrm = sqrtf(s);
    Fu[(size_t)i * 64 + c] = fn / fmaxf(nrm, EPSf);
}

// Edge cosine distance y_e = clip(1 - <Fu_i, Fu_j>, 0, 2) + histogram.
__global__ void k_edge(const float* __restrict__ Fu, const int* __restrict__ rowptr,
                       const int* __restrict__ rowIdx, const int* __restrict__ colIdx,
                       float* __restrict__ y_e, unsigned int* __restrict__ hist) {
    int nE = rowptr[N_NODES];
    int stride = gridDim.x * blockDim.x;
    for (int e = blockIdx.x * blockDim.x + threadIdx.x; e < nE; e += stride) {
        int i = rowIdx[e], j = colIdx[e];
        const float4* fi = (const float4*)(Fu + (size_t)i * 64);
        const float4* fj = (const float4*)(Fu + (size_t)j * 64);
        float d = 0.0f;
#pragma unroll
        for (int q = 0; q < 16; q++) {
            float4 a = fi[q], b = fj[q];
            d += a.x * b.x + a.y * b.y + a.z * b.z + a.w * b.w;
        }
        float y = 1.0f - d;
        y = fminf(fmaxf(y, 0.0f), 2.0f);
        y_e[e] = y;
        int bin = (int)(y * 32768.0f);
        if (bin > NBINS - 1) bin = NBINS - 1;
        atomicAdd(&hist[bin], 1u);
    }
}

// Histogram rank-select the 0.75 nanquantile (linear interp between order
// stats i0, i0+1 with h = 0.75*(nE-1)); then compute lam_combined scalar.
__global__ void k_quant(const unsigned int* __restrict__ hist,
                        const int* __restrict__ rowptr,
                        const float* __restrict__ lg0, const float* __restrict__ rdec,
                        const float* __restrict__ ralpha, int kiter,
                        float* __restrict__ scal) {
    __shared__ unsigned int psum[1024];
    __shared__ float vv[2];
    int t = threadIdx.x;
    unsigned int s = 0;
    for (int b = 0; b < 64; b++) s += hist[t * 64 + b];
    psum[t] = s;
    __syncthreads();
    for (int off = 1; off < 1024; off <<= 1) {
        unsigned int x = 0;
        if (t >= off) x = psum[t - off];
        __syncthreads();
        psum[t] += x;
        __syncthreads();
    }
    int nE = rowptr[N_NODES];
    double h = 0.75 * (double)(nE - 1);
    long long i0 = (long long)h;
    float frac = (float)(h - (double)i0);
    unsigned int r0 = (unsigned int)i0, r1 = (unsigned int)(i0 + 1);
    unsigned int cum = (t == 0) ? 0u : psum[t - 1];
    for (int b = 0; b < 64; b++) {
        unsigned int c = hist[t * 64 + b];
        unsigned int lo = cum;
        cum += c;
        if (c) {
            float v = ((float)(t * 64 + b) + 0.5f) * (2.0f / (float)NBINS);
            if (lo <= r0 && r0 < cum) vv[0] = v;
            if (lo <= r1 && r1 < cum) vv[1] = v;
        }
    }
    __syncthreads();
    if (t == 0) {
        float gd = vv[0] + frac * (vv[1] - vv[0]);
        gd = fmaxf(gd, EPSf);
        float alpha = 1.0f / (1.0f + expf(-ralpha[0]));
        float g0 = expf(lg0[0]);
        float r = 1.0f / (1.0f + expf(-rdec[0]));
        float gp = g0;
        for (int q = 0; q < kiter; q++) gp *= r;
        scal[0] = alpha * (gp / SCAD_Af) + (1.0f - alpha) * (gd / SCAD_Af);
    }
}

// Sparse propagation: one wave per row, lane = output channel.
// Fc_new_i = (sum_j W_ij * Atil_ij * Fc_j + lam*F0_i) / Q_i,
// Q_i = (sum_j W_ij)/D_i + lam.
__global__ void k_prop(const int* __restrict__ rowptr, const int* __restrict__ colIdx,
                       const float* __restrict__ y_e, const float* __restrict__ Fc,
                       const float* __restrict__ F0, const float* __restrict__ D,
                       const float* __restrict__ isD, const float* __restrict__ scal,
                       float* __restrict__ Fout) {
    int gid = blockIdx.x * blockDim.x + threadIdx.x;
    int i = gid >> 6, c = gid & 63;
    float lamc = scal[0];
    const float lam = (float)(1.0 / 0.9 - 1.0);
    int e0 = rowptr[i], e1 = rowptr[i + 1];
    float isdi = isD[i];
    float acc = 0.0f, wsum = 0.0f;
    for (int e = e0; e < e1; e++) {
        int j = colIdx[e];
        float y = y_e[e];
        float w;
        if (y <= lamc) w = 1.0f;
        else if (y <= SCAD_Af * lamc)
            w = (SCAD_Af * lamc - y) / ((SCAD_Af - 1.0f) * fmaxf(y, EPSf));
        else w = 0.0f;
        wsum += w;
        acc += w * isdi * isD[j] * Fc[(size_t)j * 64 + c];
    }
    float Q = wsum / D[i] + lam;
    Fout[(size_t)i * 64 + c] = acc / Q + lam * F0[(size_t)i * 64 + c] / Q;
}

// ---------------------------------------------------------------------------
extern "C" void kernel_launch(void* const* d_in, const int* in_sizes, int n_in,
                              void* d_out, int out_size, void* d_ws, size_t ws_size,
                              hipStream_t stream) {
    const float* A      = (const float*)d_in[0];
    const float* X      = (const float*)d_in[1];
    const float* W1     = (const float*)d_in[2];
    const float* b1     = (const float*)d_in[3];
    const float* W2     = (const float*)d_in[4];
    const float* b2     = (const float*)d_in[5];
    const float* lg0    = (const float*)d_in[6];
    const float* rdec   = (const float*)d_in[7];
    const float* ralpha = (const float*)d_in[8];
    float* out = (float*)d_out;

    char* w = (char*)d_ws;
    size_t off = 0;
    auto carve = [&](size_t bytes) -> char* {
        char* p = w + off;
        off += (bytes + 255) & ~(size_t)255;
        return p;
    };
    int*      rowcnt = (int*)carve(N_NODES * 4);
    int*      rowptr = (int*)carve((N_NODES + 16) * 4);
    int*      rowIdx = (int*)carve(MAXE * 4);
    int*      colIdx = (int*)carve(MAXE * 4);
    float*    y_e    = (float*)carve(MAXE * 4);
    unsigned* hist   = (unsigned*)carve(NBINS * 4);
    float*    D      = (float*)carve(N_NODES * 4);
    float*    isD    = (float*)carve(N_NODES * 4);
    float*    Fu     = (float*)carve((size_t)N_NODES * 64 * 4);
    float*    H1     = (float*)carve((size_t)N_NODES * H_DIM * 4);
    float*    F0     = (float*)carve((size_t)N_NODES * 64 * 4);
    float*    FcA    = (float*)carve((size_t)N_NODES * 64 * 4);
    float*    FcB    = (float*)carve((size_t)N_NODES * 64 * 4);
    float*    scal   = (float*)carve(256);

    k_deg<<<dim3(N_NODES), dim3(256), 0, stream>>>(A, rowcnt, D, isD);
    k_scan<<<dim3(1), dim3(1024), 0, stream>>>(rowcnt, rowptr);
    k_fill<<<dim3(N_NODES), dim3(256), 0, stream>>>(A, rowptr, rowIdx, colIdx);

    // MLP: H1 = relu(X@W1 + b1); F0 = H1@W2 + b2
    k_gemm<H_DIM, IN_DIM, true><<<dim3(H_DIM / 64, N_NODES / 64), dim3(256), 0, stream>>>(X, W1, b1, H1);
    k_gemm<OUT_DIM, H_DIM, false><<<dim3(1, N_NODES / 64), dim3(256), 0, stream>>>(H1, W2, b2, F0);

    const float* fin = F0;
    float* fouts[4] = {FcA, FcB, FcA, out};
    for (int k = 0; k < 4; k++) {
        k_norm<<<dim3(1024), dim3(256), 0, stream>>>(fin, isD, Fu);
        hipMemsetAsync(hist, 0, NBINS * 4, stream);
        k_edge<<<dim3(2048), dim3(256), 0, stream>>>(Fu, rowptr, rowIdx, colIdx, y_e, hist);
        k_quant<<<dim3(1), dim3(1024), 0, stream>>>(hist, rowptr, lg0, rdec, ralpha, k, scal);
        k_prop<<<dim3(1024), dim3(256), 0, stream>>>(rowptr, colIdx, y_e, fin, F0, D, isD, scal, fouts[k]);
        fin = fouts[k];
    }
}